// Round 2
// baseline (1891.202 us; speedup 1.0000x reference)
//
#include <hip/hip_runtime.h>
#include <hip/hip_bf16.h>

typedef __bf16 bf16x8_t __attribute__((ext_vector_type(8)));
typedef float f32x4_t __attribute__((ext_vector_type(4)));
using bf16 = __hip_bfloat16;

#define EMB 512
#define NTOK 32768           // B*T = 8*4096
#define NROW 262144          // B*T*H
#define SQRT_M_INV 0.17677669529663687f

// ---------------- fp32 -> bf16 ----------------
__global__ __launch_bounds__(256) void f2b_kernel(const float* __restrict__ in,
                                                  bf16* __restrict__ out, int n) {
  int i = blockIdx.x * 256 + threadIdx.x;
  if (i < n) out[i] = __float2bfloat16(in[i]);
}

// ---------------- LayerNorm (512 cols), fp32 in -> bf16 out ----------------
// block = 256 (4 waves), one row per wave; grid = NTOK/4
__global__ __launch_bounds__(256) void ln_kernel(const float* __restrict__ x,
                                                 const float* __restrict__ g,
                                                 const float* __restrict__ bt,
                                                 bf16* __restrict__ out) {
  int lane = threadIdx.x & 63;
  int row = blockIdx.x * 4 + (threadIdx.x >> 6);
  const float* xr = x + (size_t)row * EMB;
  float4 v0 = ((const float4*)xr)[lane * 2];
  float4 v1 = ((const float4*)xr)[lane * 2 + 1];
  float s = v0.x + v0.y + v0.z + v0.w + v1.x + v1.y + v1.z + v1.w;
#pragma unroll
  for (int o = 32; o; o >>= 1) s += __shfl_xor(s, o);
  float mu = s * (1.0f / 512.0f);
  float vs = 0.f, d;
  d = v0.x - mu; vs += d * d;  d = v0.y - mu; vs += d * d;
  d = v0.z - mu; vs += d * d;  d = v0.w - mu; vs += d * d;
  d = v1.x - mu; vs += d * d;  d = v1.y - mu; vs += d * d;
  d = v1.z - mu; vs += d * d;  d = v1.w - mu; vs += d * d;
#pragma unroll
  for (int o = 32; o; o >>= 1) vs += __shfl_xor(vs, o);
  float rstd = rsqrtf(vs * (1.0f / 512.0f) + 1e-5f);
  float4 g0 = ((const float4*)g)[lane * 2], g1 = ((const float4*)g)[lane * 2 + 1];
  float4 b0 = ((const float4*)bt)[lane * 2], b1 = ((const float4*)bt)[lane * 2 + 1];
  alignas(16) bf16 o8[8];
  o8[0] = __float2bfloat16((v0.x - mu) * rstd * g0.x + b0.x);
  o8[1] = __float2bfloat16((v0.y - mu) * rstd * g0.y + b0.y);
  o8[2] = __float2bfloat16((v0.z - mu) * rstd * g0.z + b0.z);
  o8[3] = __float2bfloat16((v0.w - mu) * rstd * g0.w + b0.w);
  o8[4] = __float2bfloat16((v1.x - mu) * rstd * g1.x + b1.x);
  o8[5] = __float2bfloat16((v1.y - mu) * rstd * g1.y + b1.y);
  o8[6] = __float2bfloat16((v1.z - mu) * rstd * g1.z + b1.z);
  o8[7] = __float2bfloat16((v1.w - mu) * rstd * g1.w + b1.w);
  *(uint4*)(out + (size_t)row * EMB + lane * 8) = *(const uint4*)o8;
}

// ---------------- MFMA bf16 GEMM: C[M,N] = A[M,K] * W[N,K]^T + epilogue ------
// OP 0: outF = acc + bias          (fp32 out)
// OP 1: outF = acc + bias + res    (fp32 out)
// OP 2: outB = gelu(acc + bias)    (bf16 out, exact gelu)
template <int BM, int BN, int WM, int WN, int OP>
__global__ __launch_bounds__(256) void gemm_bt(const bf16* __restrict__ A,
                                               const bf16* __restrict__ W,
                                               const float* __restrict__ bias,
                                               const float* __restrict__ res,
                                               float* __restrict__ outF,
                                               bf16* __restrict__ outB,
                                               int M, int N, int K) {
  constexpr int BK = 32;
  constexpr int LDT = BK + 8;  // 40 elems -> 80B rows (16B-aligned)
  constexpr int TM = BM / WM, TN = BN / WN;
  constexpr int NI = TM / 16, NJ = TN / 16;
  alignas(16) __shared__ bf16 As[BM * LDT];
  alignas(16) __shared__ bf16 Ws[BN * LDT];
  int t = threadIdx.x;
  int lane = t & 63, wid = t >> 6;
  int wm = wid % WM, wn = wid / WM;
  int bm = blockIdx.x * BM, bn = blockIdx.y * BN;
  int lr = lane & 15;   // row (A) / col (B) within 16
  int lq = lane >> 4;   // quad 0..3

  f32x4_t acc[NI][NJ];
#pragma unroll
  for (int i = 0; i < NI; ++i)
#pragma unroll
    for (int j = 0; j < NJ; ++j)
#pragma unroll
      for (int r = 0; r < 4; ++r) acc[i][j][r] = 0.f;

  for (int k0 = 0; k0 < K; k0 += BK) {
#pragma unroll
    for (int p = 0; p < BM * BK / 2048; ++p) {
      int ei = t * 8 + p * 2048;
      int r = ei >> 5, c = ei & 31;
      *(uint4*)&As[r * LDT + c] = *(const uint4*)&A[(size_t)(bm + r) * K + k0 + c];
    }
#pragma unroll
    for (int p = 0; p < BN * BK / 2048; ++p) {
      int ei = t * 8 + p * 2048;
      int r = ei >> 5, c = ei & 31;
      *(uint4*)&Ws[r * LDT + c] = *(const uint4*)&W[(size_t)(bn + r) * K + k0 + c];
    }
    __syncthreads();
    bf16x8_t afr[NI], bfr[NJ];
#pragma unroll
    for (int i = 0; i < NI; ++i)
      afr[i] = *(const bf16x8_t*)&As[(wm * TM + i * 16 + lr) * LDT + lq * 8];
#pragma unroll
    for (int j = 0; j < NJ; ++j)
      bfr[j] = *(const bf16x8_t*)&Ws[(wn * TN + j * 16 + lr) * LDT + lq * 8];
#pragma unroll
    for (int i = 0; i < NI; ++i)
#pragma unroll
      for (int j = 0; j < NJ; ++j)
        acc[i][j] = __builtin_amdgcn_mfma_f32_16x16x32_bf16(afr[i], bfr[j], acc[i][j], 0, 0, 0);
    __syncthreads();
  }

#pragma unroll
  for (int i = 0; i < NI; ++i)
#pragma unroll
    for (int j = 0; j < NJ; ++j) {
      int gn = bn + wn * TN + j * 16 + lr;
      float bv = bias[gn];
#pragma unroll
      for (int r = 0; r < 4; ++r) {
        int gm = bm + wm * TM + i * 16 + lq * 4 + r;
        float v = acc[i][j][r] + bv;
        size_t off = (size_t)gm * N + gn;
        if (OP == 0) {
          outF[off] = v;
        } else if (OP == 1) {
          outF[off] = v + res[off];
        } else {
          float gg = 0.5f * v * (1.0f + erff(v * 0.70710678118654752f));
          outB[off] = __float2bfloat16(gg);
        }
      }
    }
}

// ---------------- Fused KQV GEMM + prm_exp ----------------------------------
// grid = NROW/64 blocks, 256 threads. Per block: 64 rows.
// Computes kqv[64,192] = h[64,64] @ kqv_w[192,64]^T + b via MFMA into an LDS
// fp32 tile, then kp/qp = exp(w.k - |k|^2/2)/sqrt(M) (fp32) and v (bf16).
__global__ __launch_bounds__(256) void kqv_prm_kernel(
    const bf16* __restrict__ A,      // [NROW,64] LN1 out
    const bf16* __restrict__ Wk,     // [192,64]
    const float* __restrict__ bias,  // [192]
    const float* __restrict__ wrf,   // [32,64] random features
    float* __restrict__ kp, float* __restrict__ qp,
    bf16* __restrict__ vout) {       // [NROW,64]
  constexpr int LDA = 72;   // bf16 elems per staged row
  constexpr int LDK = 193;  // fp32 elems per kqvs row (odd -> conflict-free)
  alignas(16) __shared__ char u_raw[64 * LDK * 4];  // union: As+Ws | kqvs
  alignas(16) __shared__ float w_s[32][65];
  __shared__ float xd_s[64][2];
  bf16* As = (bf16*)u_raw;                     // 64*72*2   = 9216 B
  bf16* Ws = (bf16*)(u_raw + 64 * LDA * 2);    // 192*72*2  = 27648 B
  float* kqvs = (float*)u_raw;                 // 64*193*4  = 49408 B

  int t = threadIdx.x;
  int lane = t & 63, wid = t >> 6;
  int wm = wid & 1, wn = wid >> 1;  // 2x2 wave grid: rows 32/wave, cols 96/wave
  int lr = lane & 15, lq = lane >> 4;
  size_t row0 = (size_t)blockIdx.x * 64;

  // stage random features (2048 floats)
#pragma unroll
  for (int p = 0; p < 8; ++p) {
    int idx = t + p * 256;
    w_s[idx >> 6][idx & 63] = wrf[idx];
  }
  // stage A tile (64x64 bf16) and W tile (192x64 bf16)
#pragma unroll
  for (int p = 0; p < 2; ++p) {
    int ei = (t + p * 256) * 8;
    int r = ei >> 6, c = ei & 63;
    *(uint4*)&As[r * LDA + c] = *(const uint4*)&A[(row0 + r) * 64 + c];
  }
#pragma unroll
  for (int p = 0; p < 6; ++p) {
    int ei = (t + p * 256) * 8;
    int r = ei >> 6, c = ei & 63;
    *(uint4*)&Ws[r * LDA + c] = *(const uint4*)&Wk[r * 64 + c];
  }
  __syncthreads();

  f32x4_t acc[2][6];
#pragma unroll
  for (int i = 0; i < 2; ++i)
#pragma unroll
    for (int j = 0; j < 6; ++j)
#pragma unroll
      for (int r = 0; r < 4; ++r) acc[i][j][r] = 0.f;

#pragma unroll
  for (int ks = 0; ks < 2; ++ks) {
    bf16x8_t af[2], bfr[6];
#pragma unroll
    for (int i = 0; i < 2; ++i)
      af[i] = *(const bf16x8_t*)&As[(wm * 32 + i * 16 + lr) * LDA + ks * 32 + lq * 8];
#pragma unroll
    for (int j = 0; j < 6; ++j)
      bfr[j] = *(const bf16x8_t*)&Ws[(wn * 96 + j * 16 + lr) * LDA + ks * 32 + lq * 8];
#pragma unroll
    for (int i = 0; i < 2; ++i)
#pragma unroll
      for (int j = 0; j < 6; ++j)
        acc[i][j] = __builtin_amdgcn_mfma_f32_16x16x32_bf16(af[i], bfr[j], acc[i][j], 0, 0, 0);
  }
  __syncthreads();  // done reading As/Ws; reuse as kqvs

  // write acc + bias into LDS fp32 tile (C/D layout: col=lane&15, row=quad*4+r)
#pragma unroll
  for (int i = 0; i < 2; ++i)
#pragma unroll
    for (int j = 0; j < 6; ++j) {
      int col = wn * 96 + j * 16 + lr;
      float bv = bias[col];
#pragma unroll
      for (int r = 0; r < 4; ++r)
        kqvs[(wm * 32 + i * 16 + lq * 4 + r) * LDK + col] = acc[i][j][r] + bv;
    }
  __syncthreads();

  // v out (cols 128..191), bf16
#pragma unroll
  for (int p = 0; p < 16; ++p) {
    int idx = t + p * 256;
    int r = idx >> 6, c = idx & 63;
    vout[(row0 + r) * 64 + c] = __float2bfloat16(kqvs[r * LDK + 128 + c]);
  }
  // xd = 0.5*|z|^2 per (row, k/q)
  if (t < 128) {
    int r = t & 63, sel = t >> 6;
    const float* kv = &kqvs[r * LDK + sel * 64];
    float xd = 0.f;
#pragma unroll
    for (int e = 0; e < 64; ++e) xd += kv[e] * kv[e];
    xd_s[r][sel] = 0.5f * xd;
  }
  __syncthreads();

  // dots: thread -> (m = t&31, rows rr*8..rr*8+7), both k and q
  int m = t & 31, rr = t >> 5;
#pragma unroll
  for (int sel = 0; sel < 2; ++sel) {
    float* outp = sel ? qp : kp;
#pragma unroll
    for (int rb = 0; rb < 8; ++rb) {
      int r = rr * 8 + rb;
      const float* kv = &kqvs[r * LDK + sel * 64];
      float dot = 0.f;
#pragma unroll
      for (int e = 0; e < 64; ++e) dot += kv[e] * w_s[m][e];
      outp[(row0 + r) * 32 + m] = __expf(dot - xd_s[r][sel]) * SQRT_M_INV;
    }
  }
}

// ---------------- kptv + kp_sum reduction over T -----------------------------
// grid (64 bh, 16 chunks of 256 tokens), block 256
__global__ __launch_bounds__(256) void kptv_kernel(const bf16* __restrict__ v,
                                                   const float* __restrict__ kp,
                                                   float* __restrict__ kptv,
                                                   float* __restrict__ kpsum) {
  int bh = blockIdx.x, chunk = blockIdx.y;
  int b = bh >> 3, h = bh & 7;
  alignas(16) __shared__ float v_s[8][64];
  alignas(16) __shared__ float kp_s[8][32];
  int t = threadIdx.x;
  int e = t & 63, g = t >> 6;  // g: 0..3 -> m-block of 8
  float acc[8] = {0.f, 0.f, 0.f, 0.f, 0.f, 0.f, 0.f, 0.f};
  float accs = 0.f;
  for (int it = 0; it < 32; ++it) {
    int tok0 = chunk * 256 + it * 8;
    __syncthreads();
    {
      int r = t >> 5, c = t & 31;
      size_t grow = ((size_t)(b * 4096 + tok0 + r) * 8 + h);
      unsigned pk = *(const unsigned*)(v + grow * 64 + c * 2);
      __hip_bfloat162 p2 = *reinterpret_cast<__hip_bfloat162*>(&pk);
      v_s[r][c * 2] = __bfloat162float(p2.x);
      v_s[r][c * 2 + 1] = __bfloat162float(p2.y);
      kp_s[r][c] = kp[grow * 32 + c];
    }
    __syncthreads();
#pragma unroll
    for (int r = 0; r < 8; ++r) {
      float vv = v_s[r][e];
      float4 k0 = *(const float4*)&kp_s[r][g * 8];
      float4 k1 = *(const float4*)&kp_s[r][g * 8 + 4];
      acc[0] += vv * k0.x; acc[1] += vv * k0.y; acc[2] += vv * k0.z; acc[3] += vv * k0.w;
      acc[4] += vv * k1.x; acc[5] += vv * k1.y; acc[6] += vv * k1.z; acc[7] += vv * k1.w;
    }
    if (t < 32) {
#pragma unroll
      for (int r = 0; r < 8; ++r) accs += kp_s[r][t];
    }
  }
  size_t basep = ((size_t)bh * 64 + e) * 32 + g * 8;
#pragma unroll
  for (int j = 0; j < 8; ++j) atomicAdd(&kptv[basep + j], acc[j]);
  if (t < 32) atomicAdd(&kpsum[bh * 32 + t], accs);
}

// ---------------- y = (qp . kptv) / (qp . kpsum), bf16 out -------------------
// grid (64 bh, 8 chunks of 512 tokens), block 256
__global__ __launch_bounds__(256) void y_kernel(const float* __restrict__ qp,
                                                const float* __restrict__ kptv,
                                                const float* __restrict__ kpsum,
                                                bf16* __restrict__ y) {
  int bh = blockIdx.x, chunk = blockIdx.y;
  int b = bh >> 3, h = bh & 7;
  alignas(16) __shared__ float kptv_s[64][32];
  alignas(16) __shared__ float ks_s[32];
  alignas(16) __shared__ float qp_s[16][32];
  int t = threadIdx.x;
#pragma unroll
  for (int p = 0; p < 2; ++p) {
    int fi = t + p * 256;  // 512 float4s
    ((float4*)kptv_s)[fi] = ((const float4*)(kptv + (size_t)bh * 2048))[fi];
  }
  if (t < 32) ks_s[t] = kpsum[bh * 32 + t];
  int e = t & 63, iq = t >> 6;
  for (int grp = 0; grp < 32; ++grp) {
    int tok0 = chunk * 512 + grp * 16;
    __syncthreads();
    if (t < 128) {
      int r = t >> 3, c4 = t & 7;
      size_t grow = ((size_t)(b * 4096 + tok0 + r) * 8 + h);
      *(float4*)&qp_s[r][c4 * 4] = *(const float4*)(qp + grow * 32 + c4 * 4);
    }
    __syncthreads();
#pragma unroll
    for (int i0 = 0; i0 < 4; ++i0) {
      int i = iq + i0 * 4;
      float dot = 0.f, dd = 0.f;
#pragma unroll
      for (int m = 0; m < 32; m += 4) {
        float4 qq = *(const float4*)&qp_s[i][m];
        float4 kk = *(const float4*)&kptv_s[e][m];
        float4 ss = *(const float4*)&ks_s[m];
        dot += qq.x * kk.x + qq.y * kk.y + qq.z * kk.z + qq.w * kk.w;
        dd  += qq.x * ss.x + qq.y * ss.y + qq.z * ss.z + qq.w * ss.w;
      }
      int tok = tok0 + i;
      y[(size_t)(b * 4096 + tok) * EMB + h * 64 + e] = __float2bfloat16(dot / dd);
    }
  }
}

extern "C" void kernel_launch(void* const* d_in, const int* in_sizes, int n_in,
                              void* d_out, int out_size, void* d_ws, size_t ws_size,
                              hipStream_t stream) {
  const float* x      = (const float*)d_in[0];
  const float* w      = (const float*)d_in[1];
  const float* kqv_w  = (const float*)d_in[2];
  const float* kqv_b  = (const float*)d_in[3];
  const float* proj_w = (const float*)d_in[4];
  const float* proj_b = (const float*)d_in[5];
  const float* ln1_g  = (const float*)d_in[6];
  const float* ln1_b  = (const float*)d_in[7];
  const float* ln2_g  = (const float*)d_in[8];
  const float* ln2_b  = (const float*)d_in[9];
  const float* mlp_w1 = (const float*)d_in[10];
  const float* mlp_b1 = (const float*)d_in[11];
  const float* mlp_w2 = (const float*)d_in[12];
  const float* mlp_b2 = (const float*)d_in[13];
  float* out = (float*)d_out;

  char* ws = (char*)d_ws;
  size_t off = 0;
  auto alloc = [&](size_t bytes) -> void* {
    void* p = ws + off;
    off = (off + bytes + 255) & ~(size_t)255;
    return p;
  };

  // Total workspace: ~133 MiB
  bf16* kqv_wb  = (bf16*)alloc(12288 * 2);
  bf16* proj_wb = (bf16*)alloc(262144 * 2);
  bf16* w1b     = (bf16*)alloc(1048576 * 2);
  bf16* w2b     = (bf16*)alloc(1048576 * 2);
  bf16* hb      = (bf16*)alloc((size_t)NTOK * EMB * 2);   // LN1 out; reused as y
  bf16* yb      = hb;
  float* qpb    = (float*)alloc((size_t)NROW * 32 * 4);   // reused as h2 (bf16)
  bf16* h2b     = (bf16*)qpb;
  float* kpb    = (float*)alloc((size_t)NROW * 32 * 4);   // reused as hid chunk (bf16)
  bf16* hidb    = (bf16*)kpb;
  bf16* vb      = (bf16*)alloc((size_t)NROW * 64 * 2);
  float* kptvb  = (float*)alloc(64 * 64 * 32 * 4);
  float* kpsumb = (float*)alloc(64 * 32 * 4);             // contiguous after kptvb

  // 1) weights -> bf16
  f2b_kernel<<<48, 256, 0, stream>>>(kqv_w, kqv_wb, 12288);
  f2b_kernel<<<1024, 256, 0, stream>>>(proj_w, proj_wb, 262144);
  f2b_kernel<<<4096, 256, 0, stream>>>(mlp_w1, w1b, 1048576);
  f2b_kernel<<<4096, 256, 0, stream>>>(mlp_w2, w2b, 1048576);

  // 2) LN1: x -> h (bf16)
  ln_kernel<<<NTOK / 4, 256, 0, stream>>>(x, ln1_g, ln1_b, hb);

  // 3) fused KQV GEMM + prm_exp -> kp, qp (fp32), v (bf16)
  kqv_prm_kernel<<<NROW / 64, 256, 0, stream>>>(hb, kqv_wb, kqv_b, w, kpb, qpb, vb);

  // 4) kptv + kp_sum (atomic accumulate; zero first)
  hipMemsetAsync(kptvb, 0, (size_t)64 * 64 * 32 * 4 + 64 * 32 * 4, stream);
  kptv_kernel<<<dim3(64, 16), 256, 0, stream>>>(vb, kpb, kptvb, kpsumb);

  // 5) y (bf16, token-major [NTOK, 512]) -> reuses hb
  y_kernel<<<dim3(64, 8), 256, 0, stream>>>(qpb, kptvb, kpsumb, yb);

  // 6) proj GEMM + residual: d_out = y @ proj_w^T + proj_b + x
  gemm_bt<128, 128, 2, 2, 1><<<dim3(NTOK / 128, 4), 256, 0, stream>>>(
      yb, proj_wb, proj_b, x, out, nullptr, NTOK, 512, 512);

  // 7) LN2: d_out -> h2 (bf16, reuses qp region)
  ln_kernel<<<NTOK / 4, 256, 0, stream>>>(out, ln2_g, ln2_b, h2b);

  // 8) MLP in 4 token-chunks of 8192 (hid chunk reuses kp region, 33.5 MB)
  for (int c = 0; c < 4; ++c) {
    const bf16* h2c = h2b + (size_t)c * 8192 * 512;
    float* outc = out + (size_t)c * 8192 * 512;
    gemm_bt<128, 128, 2, 2, 2><<<dim3(64, 16), 256, 0, stream>>>(
        h2c, w1b, mlp_b1, nullptr, nullptr, hidb, 8192, 2048, 512);
    gemm_bt<128, 128, 2, 2, 1><<<dim3(64, 4), 256, 0, stream>>>(
        hidb, w2b, mlp_b2, outc, outc, nullptr, 8192, 512, 2048);
  }
}

// Round 3
// 1084.689 us; speedup vs baseline: 1.7435x; 1.7435x over previous
//
#include <hip/hip_runtime.h>
#include <hip/hip_bf16.h>

typedef __bf16 bf16x8_t __attribute__((ext_vector_type(8)));
typedef float f32x4_t __attribute__((ext_vector_type(4)));
using bf16 = __hip_bfloat16;

#define EMB 512
#define NTOK 32768           // B*T = 8*4096
#define NROW 262144          // B*T*H
#define SQRT_M_INV 0.17677669529663687f

// async 16B global -> LDS (wave-uniform base + lane*16; thread-order contiguous)
__device__ __forceinline__ void gload16(const void* g, void* l) {
  __builtin_amdgcn_global_load_lds((const __attribute__((address_space(1))) void*)g,
                                   (__attribute__((address_space(3))) void*)l, 16, 0, 0);
}

// ---------------- fp32 -> bf16 ----------------
__global__ __launch_bounds__(256) void f2b_kernel(const float* __restrict__ in,
                                                  bf16* __restrict__ out, int n) {
  int i = blockIdx.x * 256 + threadIdx.x;
  if (i < n) out[i] = __float2bfloat16(in[i]);
}

// ---------------- LayerNorm (512 cols), fp32 in -> bf16 out ----------------
__global__ __launch_bounds__(256) void ln_kernel(const float* __restrict__ x,
                                                 const float* __restrict__ g,
                                                 const float* __restrict__ bt,
                                                 bf16* __restrict__ out) {
  int lane = threadIdx.x & 63;
  int row = blockIdx.x * 4 + (threadIdx.x >> 6);
  const float* xr = x + (size_t)row * EMB;
  float4 v0 = ((const float4*)xr)[lane * 2];
  float4 v1 = ((const float4*)xr)[lane * 2 + 1];
  float s = v0.x + v0.y + v0.z + v0.w + v1.x + v1.y + v1.z + v1.w;
#pragma unroll
  for (int o = 32; o; o >>= 1) s += __shfl_xor(s, o);
  float mu = s * (1.0f / 512.0f);
  float vs = 0.f, d;
  d = v0.x - mu; vs += d * d;  d = v0.y - mu; vs += d * d;
  d = v0.z - mu; vs += d * d;  d = v0.w - mu; vs += d * d;
  d = v1.x - mu; vs += d * d;  d = v1.y - mu; vs += d * d;
  d = v1.z - mu; vs += d * d;  d = v1.w - mu; vs += d * d;
#pragma unroll
  for (int o = 32; o; o >>= 1) vs += __shfl_xor(vs, o);
  float rstd = rsqrtf(vs * (1.0f / 512.0f) + 1e-5f);
  float4 g0 = ((const float4*)g)[lane * 2], g1 = ((const float4*)g)[lane * 2 + 1];
  float4 b0 = ((const float4*)bt)[lane * 2], b1 = ((const float4*)bt)[lane * 2 + 1];
  alignas(16) bf16 o8[8];
  o8[0] = __float2bfloat16((v0.x - mu) * rstd * g0.x + b0.x);
  o8[1] = __float2bfloat16((v0.y - mu) * rstd * g0.y + b0.y);
  o8[2] = __float2bfloat16((v0.z - mu) * rstd * g0.z + b0.z);
  o8[3] = __float2bfloat16((v0.w - mu) * rstd * g0.w + b0.w);
  o8[4] = __float2bfloat16((v1.x - mu) * rstd * g1.x + b1.x);
  o8[5] = __float2bfloat16((v1.y - mu) * rstd * g1.y + b1.y);
  o8[6] = __float2bfloat16((v1.z - mu) * rstd * g1.z + b1.z);
  o8[7] = __float2bfloat16((v1.w - mu) * rstd * g1.w + b1.w);
  *(uint4*)(out + (size_t)row * EMB + lane * 8) = *(const uint4*)o8;
}

// ---------------- MFMA bf16 GEMM (m97-style): C = A[M,K] * W[N,K]^T ---------
// grid.x = N tiles (A-tile reuse across consecutive blocks), grid.y = M tiles.
// OP 0: outF = acc+bias   OP 1: outF = acc+bias+res   OP 2: outB = gelu(acc+bias)
template <int BM, int BN, int WM, int WN, int OP>
__global__ __launch_bounds__(256) void gemm_bt(const bf16* __restrict__ A,
                                               const bf16* __restrict__ W,
                                               const float* __restrict__ bias,
                                               const float* __restrict__ res,
                                               float* __restrict__ outF,
                                               bf16* __restrict__ outB,
                                               int M, int N, int K) {
  constexpr int BK = 32;
  constexpr int TM = BM / WM, TN = BN / WN;
  constexpr int NI = TM / 16, NJ = TN / 16;
  alignas(16) __shared__ bf16 As[BM * BK];   // unpadded: global_load_lds order
  alignas(16) __shared__ bf16 Ws[BN * BK];
  int t = threadIdx.x;
  int lane = t & 63, wid = t >> 6;
  int wm = wid % WM, wn = wid / WM;
  int bn = blockIdx.x * BN, bm = blockIdx.y * BM;
  int lr = lane & 15, lq = lane >> 4;
  const int r0 = (t * 8) >> 5, c0 = (t * 8) & 31;  // staging row/col (8 elems/thread)

  f32x4_t acc[NI][NJ];
#pragma unroll
  for (int i = 0; i < NI; ++i)
#pragma unroll
    for (int j = 0; j < NJ; ++j)
#pragma unroll
      for (int r = 0; r < 4; ++r) acc[i][j][r] = 0.f;

  for (int k0 = 0; k0 < K; k0 += BK) {
#pragma unroll
    for (int p = 0; p < BM * BK / 2048; ++p) {
      int r = r0 + p * 64;
      gload16(&A[(size_t)(bm + r) * K + k0 + c0], &As[r * BK + c0]);
    }
#pragma unroll
    for (int p = 0; p < BN * BK / 2048; ++p) {
      int r = r0 + p * 64;
      gload16(&W[(size_t)(bn + r) * K + k0 + c0], &Ws[r * BK + c0]);
    }
    __syncthreads();
    bf16x8_t afr[NI], bfr[NJ];
#pragma unroll
    for (int i = 0; i < NI; ++i)
      afr[i] = *(const bf16x8_t*)&As[(wm * TM + i * 16 + lr) * BK + lq * 8];
#pragma unroll
    for (int j = 0; j < NJ; ++j)
      bfr[j] = *(const bf16x8_t*)&Ws[(wn * TN + j * 16 + lr) * BK + lq * 8];
#pragma unroll
    for (int i = 0; i < NI; ++i)
#pragma unroll
      for (int j = 0; j < NJ; ++j)
        acc[i][j] = __builtin_amdgcn_mfma_f32_16x16x32_bf16(afr[i], bfr[j], acc[i][j], 0, 0, 0);
    __syncthreads();
  }

#pragma unroll
  for (int i = 0; i < NI; ++i)
#pragma unroll
    for (int j = 0; j < NJ; ++j) {
      int gn = bn + wn * TN + j * 16 + lr;
      float bv = bias[gn];
#pragma unroll
      for (int r = 0; r < 4; ++r) {
        int gm = bm + wm * TM + i * 16 + lq * 4 + r;
        float v = acc[i][j][r] + bv;
        size_t off = (size_t)gm * N + gn;
        if (OP == 0) {
          outF[off] = v;
        } else if (OP == 1) {
          outF[off] = v + res[off];
        } else {
          float gg = 0.5f * v * (1.0f + erff(v * 0.70710678118654752f));
          outB[off] = __float2bfloat16(gg);
        }
      }
    }
}

// ---------------- Fused KQV GEMM + prm_exp ----------------------------------
__global__ __launch_bounds__(256) void kqv_prm_kernel(
    const bf16* __restrict__ A,      // [NROW,64] LN1 out
    const bf16* __restrict__ Wk,     // [192,64]
    const float* __restrict__ bias,  // [192]
    const float* __restrict__ wrf,   // [32,64] random features
    float* __restrict__ kp, float* __restrict__ qp,
    bf16* __restrict__ vout) {       // [NROW,64]
  constexpr int LDA = 72;
  constexpr int LDK = 193;  // odd -> conflict-free fp32 tile
  alignas(16) __shared__ char u_raw[64 * LDK * 4];
  alignas(16) __shared__ float w_s[32][65];
  __shared__ float xd_s[64][2];
  bf16* As = (bf16*)u_raw;
  bf16* Ws = (bf16*)(u_raw + 64 * LDA * 2);
  float* kqvs = (float*)u_raw;

  int t = threadIdx.x;
  int lane = t & 63, wid = t >> 6;
  int wm = wid & 1, wn = wid >> 1;
  int lr = lane & 15, lq = lane >> 4;
  size_t row0 = (size_t)blockIdx.x * 64;

#pragma unroll
  for (int p = 0; p < 8; ++p) {
    int idx = t + p * 256;
    w_s[idx >> 6][idx & 63] = wrf[idx];
  }
#pragma unroll
  for (int p = 0; p < 2; ++p) {
    int ei = (t + p * 256) * 8;
    int r = ei >> 6, c = ei & 63;
    *(uint4*)&As[r * LDA + c] = *(const uint4*)&A[(row0 + r) * 64 + c];
  }
#pragma unroll
  for (int p = 0; p < 6; ++p) {
    int ei = (t + p * 256) * 8;
    int r = ei >> 6, c = ei & 63;
    *(uint4*)&Ws[r * LDA + c] = *(const uint4*)&Wk[r * 64 + c];
  }
  __syncthreads();

  f32x4_t acc[2][6];
#pragma unroll
  for (int i = 0; i < 2; ++i)
#pragma unroll
    for (int j = 0; j < 6; ++j)
#pragma unroll
      for (int r = 0; r < 4; ++r) acc[i][j][r] = 0.f;

#pragma unroll
  for (int ks = 0; ks < 2; ++ks) {
    bf16x8_t af[2], bfr[6];
#pragma unroll
    for (int i = 0; i < 2; ++i)
      af[i] = *(const bf16x8_t*)&As[(wm * 32 + i * 16 + lr) * LDA + ks * 32 + lq * 8];
#pragma unroll
    for (int j = 0; j < 6; ++j)
      bfr[j] = *(const bf16x8_t*)&Ws[(wn * 96 + j * 16 + lr) * LDA + ks * 32 + lq * 8];
#pragma unroll
    for (int i = 0; i < 2; ++i)
#pragma unroll
      for (int j = 0; j < 6; ++j)
        acc[i][j] = __builtin_amdgcn_mfma_f32_16x16x32_bf16(af[i], bfr[j], acc[i][j], 0, 0, 0);
  }
  __syncthreads();  // reuse As/Ws as kqvs

#pragma unroll
  for (int i = 0; i < 2; ++i)
#pragma unroll
    for (int j = 0; j < 6; ++j) {
      int col = wn * 96 + j * 16 + lr;
      float bv = bias[col];
#pragma unroll
      for (int r = 0; r < 4; ++r)
        kqvs[(wm * 32 + i * 16 + lq * 4 + r) * LDK + col] = acc[i][j][r] + bv;
    }
  __syncthreads();

#pragma unroll
  for (int p = 0; p < 16; ++p) {
    int idx = t + p * 256;
    int r = idx >> 6, c = idx & 63;
    vout[(row0 + r) * 64 + c] = __float2bfloat16(kqvs[r * LDK + 128 + c]);
  }
  if (t < 128) {
    int r = t & 63, sel = t >> 6;
    const float* kv = &kqvs[r * LDK + sel * 64];
    float xd = 0.f;
#pragma unroll
    for (int e = 0; e < 64; ++e) xd += kv[e] * kv[e];
    xd_s[r][sel] = 0.5f * xd;
  }
  __syncthreads();

  int m = t & 31, rr = t >> 5;
#pragma unroll
  for (int sel = 0; sel < 2; ++sel) {
    float* outp = sel ? qp : kp;
#pragma unroll
    for (int rb = 0; rb < 8; ++rb) {
      int r = rr * 8 + rb;
      const float* kv = &kqvs[r * LDK + sel * 64];
      float dot = 0.f;
#pragma unroll
      for (int e = 0; e < 64; ++e) dot += kv[e] * w_s[m][e];
      outp[(row0 + r) * 32 + m] = __expf(dot - xd_s[r][sel]) * SQRT_M_INV;
    }
  }
}

// ---------------- kptv + kp_sum reduction over T -----------------------------
__global__ __launch_bounds__(256) void kptv_kernel(const bf16* __restrict__ v,
                                                   const float* __restrict__ kp,
                                                   float* __restrict__ kptv,
                                                   float* __restrict__ kpsum) {
  int bh = blockIdx.x, chunk = blockIdx.y;
  int b = bh >> 3, h = bh & 7;
  alignas(16) __shared__ float v_s[8][64];
  alignas(16) __shared__ float kp_s[8][32];
  int t = threadIdx.x;
  int e = t & 63, g = t >> 6;
  float acc[8] = {0.f, 0.f, 0.f, 0.f, 0.f, 0.f, 0.f, 0.f};
  float accs = 0.f;
  for (int it = 0; it < 32; ++it) {
    int tok0 = chunk * 256 + it * 8;
    __syncthreads();
    {
      int r = t >> 5, c = t & 31;
      size_t grow = ((size_t)(b * 4096 + tok0 + r) * 8 + h);
      unsigned pk = *(const unsigned*)(v + grow * 64 + c * 2);
      __hip_bfloat162 p2 = *reinterpret_cast<__hip_bfloat162*>(&pk);
      v_s[r][c * 2] = __bfloat162float(p2.x);
      v_s[r][c * 2 + 1] = __bfloat162float(p2.y);
      kp_s[r][c] = kp[grow * 32 + c];
    }
    __syncthreads();
#pragma unroll
    for (int r = 0; r < 8; ++r) {
      float vv = v_s[r][e];
      float4 k0 = *(const float4*)&kp_s[r][g * 8];
      float4 k1 = *(const float4*)&kp_s[r][g * 8 + 4];
      acc[0] += vv * k0.x; acc[1] += vv * k0.y; acc[2] += vv * k0.z; acc[3] += vv * k0.w;
      acc[4] += vv * k1.x; acc[5] += vv * k1.y; acc[6] += vv * k1.z; acc[7] += vv * k1.w;
    }
    if (t < 32) {
#pragma unroll
      for (int r = 0; r < 8; ++r) accs += kp_s[r][t];
    }
  }
  size_t basep = ((size_t)bh * 64 + e) * 32 + g * 8;
#pragma unroll
  for (int j = 0; j < 8; ++j) atomicAdd(&kptv[basep + j], acc[j]);
  if (t < 32) atomicAdd(&kpsum[bh * 32 + t], accs);
}

// ---------------- y = (qp . kptv) / (qp . kpsum), bf16 out -------------------
// kptv row + kpsum in REGISTERS (R2: stride-32 LDS gave 64-way bank conflicts,
// 4.2e8 cycles). qp via same-address LDS broadcast (conflict-free).
__global__ __launch_bounds__(256) void y_kernel(const float* __restrict__ qp,
                                                const float* __restrict__ kptv,
                                                const float* __restrict__ kpsum,
                                                bf16* __restrict__ y) {
  int bh = blockIdx.x, chunk = blockIdx.y;
  int b = bh >> 3, h = bh & 7;
  alignas(16) __shared__ float qp_s[16][32];
  int t = threadIdx.x;
  int e = t & 63, iq = t >> 6;
  float kv[32], ks[32];
  {
    const float* kr = kptv + ((size_t)bh * 64 + e) * 32;
    const float* sr = kpsum + bh * 32;
#pragma unroll
    for (int m = 0; m < 32; m += 4) {
      float4 a = *(const float4*)&kr[m];
      kv[m] = a.x; kv[m + 1] = a.y; kv[m + 2] = a.z; kv[m + 3] = a.w;
      float4 s = *(const float4*)&sr[m];
      ks[m] = s.x; ks[m + 1] = s.y; ks[m + 2] = s.z; ks[m + 3] = s.w;
    }
  }
  for (int grp = 0; grp < 32; ++grp) {
    int tok0 = chunk * 512 + grp * 16;
    __syncthreads();
    if (t < 128) {
      int r = t >> 3, c4 = t & 7;
      size_t grow = ((size_t)(b * 4096 + tok0 + r) * 8 + h);
      *(float4*)&qp_s[r][c4 * 4] = *(const float4*)(qp + grow * 32 + c4 * 4);
    }
    __syncthreads();
#pragma unroll
    for (int i0 = 0; i0 < 4; ++i0) {
      int i = iq * 4 + i0;
      float dot = 0.f, dd = 0.f;
#pragma unroll
      for (int m = 0; m < 32; m += 4) {
        float4 qq = *(const float4*)&qp_s[i][m];
        dot += qq.x * kv[m] + qq.y * kv[m + 1] + qq.z * kv[m + 2] + qq.w * kv[m + 3];
        dd  += qq.x * ks[m] + qq.y * ks[m + 1] + qq.z * ks[m + 2] + qq.w * ks[m + 3];
      }
      y[(size_t)(b * 4096 + tok0 + i) * EMB + h * 64 + e] = __float2bfloat16(dot / dd);
    }
  }
}

extern "C" void kernel_launch(void* const* d_in, const int* in_sizes, int n_in,
                              void* d_out, int out_size, void* d_ws, size_t ws_size,
                              hipStream_t stream) {
  const float* x      = (const float*)d_in[0];
  const float* w      = (const float*)d_in[1];
  const float* kqv_w  = (const float*)d_in[2];
  const float* kqv_b  = (const float*)d_in[3];
  const float* proj_w = (const float*)d_in[4];
  const float* proj_b = (const float*)d_in[5];
  const float* ln1_g  = (const float*)d_in[6];
  const float* ln1_b  = (const float*)d_in[7];
  const float* ln2_g  = (const float*)d_in[8];
  const float* ln2_b  = (const float*)d_in[9];
  const float* mlp_w1 = (const float*)d_in[10];
  const float* mlp_b1 = (const float*)d_in[11];
  const float* mlp_w2 = (const float*)d_in[12];
  const float* mlp_b2 = (const float*)d_in[13];
  float* out = (float*)d_out;

  char* ws = (char*)d_ws;
  size_t off = 0;
  auto alloc = [&](size_t bytes) -> void* {
    void* p = ws + off;
    off = (off + bytes + 255) & ~(size_t)255;
    return p;
  };

  // ~133 MiB total
  bf16* kqv_wb  = (bf16*)alloc(12288 * 2);
  bf16* proj_wb = (bf16*)alloc(262144 * 2);
  bf16* w1b     = (bf16*)alloc(1048576 * 2);
  bf16* w2b     = (bf16*)alloc(1048576 * 2);
  bf16* hb      = (bf16*)alloc((size_t)NTOK * EMB * 2);   // LN1 out; reused as y
  bf16* yb      = hb;
  float* qpb    = (float*)alloc((size_t)NROW * 32 * 4);   // reused as h2 (bf16)
  bf16* h2b     = (bf16*)qpb;
  float* kpb    = (float*)alloc((size_t)NROW * 32 * 4);   // kp; +vb reused as hid
  bf16* hidb    = (bf16*)kpb;                              // spans kpb+vb (67 MB)
  bf16* vb      = (bf16*)alloc((size_t)NROW * 64 * 2);     // contiguous after kpb
  float* kptvb  = (float*)alloc(64 * 64 * 32 * 4);
  float* kpsumb = (float*)alloc(64 * 32 * 4);              // contiguous after kptvb

  // 1) weights -> bf16
  f2b_kernel<<<48, 256, 0, stream>>>(kqv_w, kqv_wb, 12288);
  f2b_kernel<<<1024, 256, 0, stream>>>(proj_w, proj_wb, 262144);
  f2b_kernel<<<4096, 256, 0, stream>>>(mlp_w1, w1b, 1048576);
  f2b_kernel<<<4096, 256, 0, stream>>>(mlp_w2, w2b, 1048576);

  // 2) LN1: x -> h (bf16)
  ln_kernel<<<NTOK / 4, 256, 0, stream>>>(x, ln1_g, ln1_b, hb);

  // 3) fused KQV GEMM + prm_exp -> kp, qp (fp32), v (bf16)
  kqv_prm_kernel<<<NROW / 64, 256, 0, stream>>>(hb, kqv_wb, kqv_b, w, kpb, qpb, vb);

  // 4) kptv + kp_sum (atomic accumulate; zero first)
  hipMemsetAsync(kptvb, 0, (size_t)64 * 64 * 32 * 4 + 64 * 32 * 4, stream);
  kptv_kernel<<<dim3(64, 16), 256, 0, stream>>>(vb, kpb, kptvb, kpsumb);

  // 5) y (bf16, token-major [NTOK, 512]) -> reuses hb
  y_kernel<<<dim3(64, 8), 256, 0, stream>>>(qpb, kptvb, kpsumb, yb);

  // 6) proj GEMM + residual: d_out = y @ proj_w^T + proj_b + x
  gemm_bt<128, 128, 2, 2, 1><<<dim3(4, NTOK / 128), 256, 0, stream>>>(
      yb, proj_wb, proj_b, x, out, nullptr, NTOK, 512, 512);

  // 7) LN2: d_out -> h2 (bf16, reuses qp region)
  ln_kernel<<<NTOK / 4, 256, 0, stream>>>(out, ln2_g, ln2_b, h2b);

  // 8) MLP in 2 token-chunks of 16384 (hid reuses kp+v regions, 67 MB)
  for (int c = 0; c < 2; ++c) {
    const bf16* h2c = h2b + (size_t)c * 16384 * 512;
    float* outc = out + (size_t)c * 16384 * 512;
    gemm_bt<128, 128, 2, 2, 2><<<dim3(16, 128), 256, 0, stream>>>(
        h2c, w1b, mlp_b1, nullptr, nullptr, hidb, 16384, 2048, 512);
    gemm_bt<128, 128, 2, 2, 1><<<dim3(4, 128), 256, 0, stream>>>(
        hidb, w2b, mlp_b2, outc, outc, nullptr, 16384, 512, 2048);
  }
}

// Round 4
// 716.173 us; speedup vs baseline: 2.6407x; 1.5146x over previous
//
#include <hip/hip_runtime.h>
#include <hip/hip_bf16.h>

typedef __bf16 bf16x8_t __attribute__((ext_vector_type(8)));
typedef float f32x4_t __attribute__((ext_vector_type(4)));
using bf16 = __hip_bfloat16;

#define EMB 512
#define NTOK 32768           // B*T = 8*4096
#define NROW 262144          // B*T*H
#define SQRT_M_INV 0.17677669529663687f

// async 16B global -> LDS (wave-uniform base + lane*16; thread-order contiguous)
__device__ __forceinline__ void gload16(const void* g, void* l) {
  __builtin_amdgcn_global_load_lds((const __attribute__((address_space(1))) void*)g,
                                   (__attribute__((address_space(3))) void*)l, 16, 0, 0);
}

// ---------------- fp32 -> bf16 ----------------
__global__ __launch_bounds__(256) void f2b_kernel(const float* __restrict__ in,
                                                  bf16* __restrict__ out, int n) {
  int i = blockIdx.x * 256 + threadIdx.x;
  if (i < n) out[i] = __float2bfloat16(in[i]);
}

// ---------------- LayerNorm (512 cols), fp32 in -> bf16 out ----------------
__global__ __launch_bounds__(256) void ln_kernel(const float* __restrict__ x,
                                                 const float* __restrict__ g,
                                                 const float* __restrict__ bt,
                                                 bf16* __restrict__ out) {
  int lane = threadIdx.x & 63;
  int row = blockIdx.x * 4 + (threadIdx.x >> 6);
  const float* xr = x + (size_t)row * EMB;
  float4 v0 = ((const float4*)xr)[lane * 2];
  float4 v1 = ((const float4*)xr)[lane * 2 + 1];
  float s = v0.x + v0.y + v0.z + v0.w + v1.x + v1.y + v1.z + v1.w;
#pragma unroll
  for (int o = 32; o; o >>= 1) s += __shfl_xor(s, o);
  float mu = s * (1.0f / 512.0f);
  float vs = 0.f, d;
  d = v0.x - mu; vs += d * d;  d = v0.y - mu; vs += d * d;
  d = v0.z - mu; vs += d * d;  d = v0.w - mu; vs += d * d;
  d = v1.x - mu; vs += d * d;  d = v1.y - mu; vs += d * d;
  d = v1.z - mu; vs += d * d;  d = v1.w - mu; vs += d * d;
#pragma unroll
  for (int o = 32; o; o >>= 1) vs += __shfl_xor(vs, o);
  float rstd = rsqrtf(vs * (1.0f / 512.0f) + 1e-5f);
  float4 g0 = ((const float4*)g)[lane * 2], g1 = ((const float4*)g)[lane * 2 + 1];
  float4 b0 = ((const float4*)bt)[lane * 2], b1 = ((const float4*)bt)[lane * 2 + 1];
  alignas(16) bf16 o8[8];
  o8[0] = __float2bfloat16((v0.x - mu) * rstd * g0.x + b0.x);
  o8[1] = __float2bfloat16((v0.y - mu) * rstd * g0.y + b0.y);
  o8[2] = __float2bfloat16((v0.z - mu) * rstd * g0.z + b0.z);
  o8[3] = __float2bfloat16((v0.w - mu) * rstd * g0.w + b0.w);
  o8[4] = __float2bfloat16((v1.x - mu) * rstd * g1.x + b1.x);
  o8[5] = __float2bfloat16((v1.y - mu) * rstd * g1.y + b1.y);
  o8[6] = __float2bfloat16((v1.z - mu) * rstd * g1.z + b1.z);
  o8[7] = __float2bfloat16((v1.w - mu) * rstd * g1.w + b1.w);
  *(uint4*)(out + (size_t)row * EMB + lane * 8) = *(const uint4*)o8;
}

// ---------------- MFMA bf16 GEMM (m97-style): C = A[M,K] * W[N,K]^T ---------
template <int BM, int BN, int WM, int WN, int OP>
__global__ __launch_bounds__(256) void gemm_bt(const bf16* __restrict__ A,
                                               const bf16* __restrict__ W,
                                               const float* __restrict__ bias,
                                               const float* __restrict__ res,
                                               float* __restrict__ outF,
                                               bf16* __restrict__ outB,
                                               int M, int N, int K) {
  constexpr int BK = 32;
  constexpr int TM = BM / WM, TN = BN / WN;
  constexpr int NI = TM / 16, NJ = TN / 16;
  alignas(16) __shared__ bf16 As[BM * BK];
  alignas(16) __shared__ bf16 Ws[BN * BK];
  int t = threadIdx.x;
  int lane = t & 63, wid = t >> 6;
  int wm = wid % WM, wn = wid / WM;
  int bn = blockIdx.x * BN, bm = blockIdx.y * BM;
  int lr = lane & 15, lq = lane >> 4;
  const int r0 = (t * 8) >> 5, c0 = (t * 8) & 31;

  f32x4_t acc[NI][NJ];
#pragma unroll
  for (int i = 0; i < NI; ++i)
#pragma unroll
    for (int j = 0; j < NJ; ++j)
#pragma unroll
      for (int r = 0; r < 4; ++r) acc[i][j][r] = 0.f;

  for (int k0 = 0; k0 < K; k0 += BK) {
#pragma unroll
    for (int p = 0; p < BM * BK / 2048; ++p) {
      int r = r0 + p * 64;
      gload16(&A[(size_t)(bm + r) * K + k0 + c0], &As[r * BK + c0]);
    }
#pragma unroll
    for (int p = 0; p < BN * BK / 2048; ++p) {
      int r = r0 + p * 64;
      gload16(&W[(size_t)(bn + r) * K + k0 + c0], &Ws[r * BK + c0]);
    }
    __syncthreads();
    bf16x8_t afr[NI], bfr[NJ];
#pragma unroll
    for (int i = 0; i < NI; ++i)
      afr[i] = *(const bf16x8_t*)&As[(wm * TM + i * 16 + lr) * BK + lq * 8];
#pragma unroll
    for (int j = 0; j < NJ; ++j)
      bfr[j] = *(const bf16x8_t*)&Ws[(wn * TN + j * 16 + lr) * BK + lq * 8];
#pragma unroll
    for (int i = 0; i < NI; ++i)
#pragma unroll
      for (int j = 0; j < NJ; ++j)
        acc[i][j] = __builtin_amdgcn_mfma_f32_16x16x32_bf16(afr[i], bfr[j], acc[i][j], 0, 0, 0);
    __syncthreads();
  }

#pragma unroll
  for (int i = 0; i < NI; ++i)
#pragma unroll
    for (int j = 0; j < NJ; ++j) {
      int gn = bn + wn * TN + j * 16 + lr;
      float bv = bias[gn];
#pragma unroll
      for (int r = 0; r < 4; ++r) {
        int gm = bm + wm * TM + i * 16 + lq * 4 + r;
        float v = acc[i][j][r] + bv;
        size_t off = (size_t)gm * N + gn;
        if (OP == 0) {
          outF[off] = v;
        } else if (OP == 1) {
          outF[off] = v + res[off];
        } else {
          float gg = 0.5f * v * (1.0f + erff(v * 0.70710678118654752f));
          outB[off] = __float2bfloat16(gg);
        }
      }
    }
}

// ---------------- Fused KQV GEMM + prm_exp (all-MFMA) ------------------------
// Per block: 64 rows. kqv tile via MFMA; z(k|q)+bias -> bf16 LDS tile;
// xd from LDS (fp32 acc); wtx = z @ wrf^T via MFMA (B-frags in registers);
// kp/qp = exp(wtx - xd)*SQRT_M_INV from C/D regs; v -> coalesced bf16 out.
__global__ __launch_bounds__(256) void kqv_prm_kernel(
    const bf16* __restrict__ A,      // [NROW,64] LN1 out
    const bf16* __restrict__ Wk,     // [192,64]
    const float* __restrict__ bias,  // [192]
    const float* __restrict__ wrf,   // [32,64] random features
    float* __restrict__ kp, float* __restrict__ qp,
    bf16* __restrict__ vout) {       // [NROW,64]
  constexpr int LDZ = 136;  // bf16 elems/row: stride 68 dwords -> 2-way max
  constexpr int LDV = 72;
  alignas(16) __shared__ char u_raw[27648];
  bf16* As  = (bf16*)u_raw;               // phase1: 64*32*2  = 4096
  bf16* Ws  = (bf16*)(u_raw + 4096);      // phase1: 192*32*2 = 12288
  bf16* zkq = (bf16*)u_raw;               // phase2: 64*136*2 = 17408
  bf16* vs  = (bf16*)(u_raw + 17408);     // phase2: 64*72*2  = 9216
  float* xd_s = (float*)(u_raw + 26624);  // phase2: 64*2*4   = 512

  int t = threadIdx.x;
  int lane = t & 63, wid = t >> 6;
  int wm = wid & 1, wn = wid >> 1;  // rows: wm*32..+32, cols: wn*96..+96
  int lr = lane & 15, lq = lane >> 4;
  size_t row0 = (size_t)blockIdx.x * 64;

  // random-feature B-fragments in registers: wfrag[mtile][kstep]
  bf16x8_t wfrag[2][2];
#pragma unroll
  for (int mt = 0; mt < 2; ++mt)
#pragma unroll
    for (int ks = 0; ks < 2; ++ks) {
      const float* src = wrf + (mt * 16 + lr) * 64 + ks * 32 + lq * 8;
#pragma unroll
      for (int jj = 0; jj < 8; ++jj) wfrag[mt][ks][jj] = (__bf16)src[jj];
    }

  f32x4_t acc[2][6];
#pragma unroll
  for (int i = 0; i < 2; ++i)
#pragma unroll
    for (int j = 0; j < 6; ++j)
#pragma unroll
      for (int r = 0; r < 4; ++r) acc[i][j][r] = 0.f;

  const int r0 = t >> 2, c0 = (t * 8) & 31;
  for (int k0 = 0; k0 < 64; k0 += 32) {
    gload16(&A[(row0 + r0) * 64 + k0 + c0], &As[r0 * 32 + c0]);
#pragma unroll
    for (int p = 0; p < 3; ++p) {
      int r = r0 + p * 64;
      gload16(&Wk[(size_t)r * 64 + k0 + c0], &Ws[r * 32 + c0]);
    }
    __syncthreads();
    bf16x8_t af[2], bfr[6];
#pragma unroll
    for (int i = 0; i < 2; ++i)
      af[i] = *(const bf16x8_t*)&As[(wm * 32 + i * 16 + lr) * 32 + lq * 8];
#pragma unroll
    for (int j = 0; j < 6; ++j)
      bfr[j] = *(const bf16x8_t*)&Ws[(wn * 96 + j * 16 + lr) * 32 + lq * 8];
#pragma unroll
    for (int i = 0; i < 2; ++i)
#pragma unroll
      for (int j = 0; j < 6; ++j)
        acc[i][j] = __builtin_amdgcn_mfma_f32_16x16x32_bf16(af[i], bfr[j], acc[i][j], 0, 0, 0);
    __syncthreads();
  }

  // epilogue 1: z (cols 0..127, bias added) -> zkq bf16; v (128..191) -> vs
#pragma unroll
  for (int i = 0; i < 2; ++i)
#pragma unroll
    for (int j = 0; j < 6; ++j) {
      int col = wn * 96 + j * 16 + lr;
      float bv = bias[col];
      int rowb = wm * 32 + i * 16 + lq * 4;
#pragma unroll
      for (int r = 0; r < 4; ++r) {
        float v = acc[i][j][r] + bv;
        if (col < 128) zkq[(rowb + r) * LDZ + col] = __float2bfloat16(v);
        else           vs[(rowb + r) * LDV + (col - 128)] = __float2bfloat16(v);
      }
    }
  __syncthreads();

  // xd = 0.5*|z|^2 per (row, sel) from bf16 z, fp32 accumulate
  if (t < 128) {
    int r = t & 63, sel = t >> 6;
    const bf16* zr = &zkq[r * LDZ + sel * 64];
    float xd = 0.f;
#pragma unroll
    for (int c = 0; c < 64; c += 8) {
      bf16x8_t z8 = *(const bf16x8_t*)&zr[c];
#pragma unroll
      for (int jj = 0; jj < 8; ++jj) { float f = (float)z8[jj]; xd += f * f; }
    }
    xd_s[r * 2 + sel] = 0.5f * xd;
  }
  __syncthreads();

  // v -> global (coalesced uint4)
#pragma unroll
  for (int p = 0; p < 2; ++p) {
    int idx = t + p * 256;            // 512 uint4s = 64 rows x 8
    int r = idx >> 3, c8 = idx & 7;
    *(uint4*)&vout[(row0 + r) * 64 + c8 * 8] = *(const uint4*)&vs[r * LDV + c8 * 8];
  }

  // wtx via MFMA: wave (wm,wn) -> rows wm*32..+32, sel=wn
  int sel = wn;
  f32x4_t aw[2][2];
#pragma unroll
  for (int i = 0; i < 2; ++i)
#pragma unroll
    for (int mt = 0; mt < 2; ++mt)
#pragma unroll
      for (int r = 0; r < 4; ++r) aw[i][mt][r] = 0.f;
#pragma unroll
  for (int ks = 0; ks < 2; ++ks) {
    bf16x8_t af2[2];
#pragma unroll
    for (int i = 0; i < 2; ++i)
      af2[i] = *(const bf16x8_t*)&zkq[(wm * 32 + i * 16 + lr) * LDZ + sel * 64 + ks * 32 + lq * 8];
#pragma unroll
    for (int i = 0; i < 2; ++i)
#pragma unroll
      for (int mt = 0; mt < 2; ++mt)
        aw[i][mt] = __builtin_amdgcn_mfma_f32_16x16x32_bf16(af2[i], wfrag[mt][ks], aw[i][mt], 0, 0, 0);
  }
  float* outp = sel ? qp : kp;
#pragma unroll
  for (int i = 0; i < 2; ++i)
#pragma unroll
    for (int mt = 0; mt < 2; ++mt) {
      int m = mt * 16 + lr;
#pragma unroll
      for (int r = 0; r < 4; ++r) {
        int row = wm * 32 + i * 16 + lq * 4 + r;
        outp[(row0 + row) * 32 + m] =
            __expf(aw[i][mt][r] - xd_s[row * 2 + sel]) * SQRT_M_INV;
      }
    }
}

// ---------------- kptv + kp_sum reduction over T -----------------------------
__global__ __launch_bounds__(256) void kptv_kernel(const bf16* __restrict__ v,
                                                   const float* __restrict__ kp,
                                                   float* __restrict__ kptv,
                                                   float* __restrict__ kpsum) {
  int bh = blockIdx.x, chunk = blockIdx.y;
  int b = bh >> 3, h = bh & 7;
  alignas(16) __shared__ float v_s[8][64];
  alignas(16) __shared__ float kp_s[8][32];
  int t = threadIdx.x;
  int e = t & 63, g = t >> 6;
  float acc[8] = {0.f, 0.f, 0.f, 0.f, 0.f, 0.f, 0.f, 0.f};
  float accs = 0.f;
  for (int it = 0; it < 32; ++it) {
    int tok0 = chunk * 256 + it * 8;
    __syncthreads();
    {
      int r = t >> 5, c = t & 31;
      size_t grow = ((size_t)(b * 4096 + tok0 + r) * 8 + h);
      unsigned pk = *(const unsigned*)(v + grow * 64 + c * 2);
      __hip_bfloat162 p2 = *reinterpret_cast<__hip_bfloat162*>(&pk);
      v_s[r][c * 2] = __bfloat162float(p2.x);
      v_s[r][c * 2 + 1] = __bfloat162float(p2.y);
      kp_s[r][c] = kp[grow * 32 + c];
    }
    __syncthreads();
#pragma unroll
    for (int r = 0; r < 8; ++r) {
      float vv = v_s[r][e];
      float4 k0 = *(const float4*)&kp_s[r][g * 8];
      float4 k1 = *(const float4*)&kp_s[r][g * 8 + 4];
      acc[0] += vv * k0.x; acc[1] += vv * k0.y; acc[2] += vv * k0.z; acc[3] += vv * k0.w;
      acc[4] += vv * k1.x; acc[5] += vv * k1.y; acc[6] += vv * k1.z; acc[7] += vv * k1.w;
    }
    if (t < 32) {
#pragma unroll
      for (int r = 0; r < 8; ++r) accs += kp_s[r][t];
    }
  }
  size_t basep = ((size_t)bh * 64 + e) * 32 + g * 8;
#pragma unroll
  for (int j = 0; j < 8; ++j) atomicAdd(&kptv[basep + j], acc[j]);
  if (t < 32) atomicAdd(&kpsum[bh * 32 + t], accs);
}

// ---------------- y = (qp . kptv) / (qp . kpsum), bf16 out -------------------
__global__ __launch_bounds__(256) void y_kernel(const float* __restrict__ qp,
                                                const float* __restrict__ kptv,
                                                const float* __restrict__ kpsum,
                                                bf16* __restrict__ y) {
  int bh = blockIdx.x, chunk = blockIdx.y;
  int b = bh >> 3, h = bh & 7;
  alignas(16) __shared__ float qp_s[16][32];
  int t = threadIdx.x;
  int e = t & 63, iq = t >> 6;
  float kv[32], ks[32];
  {
    const float* kr = kptv + ((size_t)bh * 64 + e) * 32;
    const float* sr = kpsum + bh * 32;
#pragma unroll
    for (int m = 0; m < 32; m += 4) {
      float4 a = *(const float4*)&kr[m];
      kv[m] = a.x; kv[m + 1] = a.y; kv[m + 2] = a.z; kv[m + 3] = a.w;
      float4 s = *(const float4*)&sr[m];
      ks[m] = s.x; ks[m + 1] = s.y; ks[m + 2] = s.z; ks[m + 3] = s.w;
    }
  }
  for (int grp = 0; grp < 32; ++grp) {
    int tok0 = chunk * 512 + grp * 16;
    __syncthreads();
    if (t < 128) {
      int r = t >> 3, c4 = t & 7;
      size_t grow = ((size_t)(b * 4096 + tok0 + r) * 8 + h);
      *(float4*)&qp_s[r][c4 * 4] = *(const float4*)(qp + grow * 32 + c4 * 4);
    }
    __syncthreads();
#pragma unroll
    for (int i0 = 0; i0 < 4; ++i0) {
      int i = iq * 4 + i0;
      float dot = 0.f, dd = 0.f;
#pragma unroll
      for (int m = 0; m < 32; m += 4) {
        float4 qq = *(const float4*)&qp_s[i][m];
        dot += qq.x * kv[m] + qq.y * kv[m + 1] + qq.z * kv[m + 2] + qq.w * kv[m + 3];
        dd  += qq.x * ks[m] + qq.y * ks[m + 1] + qq.z * ks[m + 2] + qq.w * ks[m + 3];
      }
      y[(size_t)(b * 4096 + tok0 + i) * EMB + h * 64 + e] = __float2bfloat16(dot / dd);
    }
  }
}

extern "C" void kernel_launch(void* const* d_in, const int* in_sizes, int n_in,
                              void* d_out, int out_size, void* d_ws, size_t ws_size,
                              hipStream_t stream) {
  const float* x      = (const float*)d_in[0];
  const float* w      = (const float*)d_in[1];
  const float* kqv_w  = (const float*)d_in[2];
  const float* kqv_b  = (const float*)d_in[3];
  const float* proj_w = (const float*)d_in[4];
  const float* proj_b = (const float*)d_in[5];
  const float* ln1_g  = (const float*)d_in[6];
  const float* ln1_b  = (const float*)d_in[7];
  const float* ln2_g  = (const float*)d_in[8];
  const float* ln2_b  = (const float*)d_in[9];
  const float* mlp_w1 = (const float*)d_in[10];
  const float* mlp_b1 = (const float*)d_in[11];
  const float* mlp_w2 = (const float*)d_in[12];
  const float* mlp_b2 = (const float*)d_in[13];
  float* out = (float*)d_out;

  char* ws = (char*)d_ws;
  size_t off = 0;
  auto alloc = [&](size_t bytes) -> void* {
    void* p = ws + off;
    off = (off + bytes + 255) & ~(size_t)255;
    return p;
  };

  // ~133 MiB total
  bf16* kqv_wb  = (bf16*)alloc(12288 * 2);
  bf16* proj_wb = (bf16*)alloc(262144 * 2);
  bf16* w1b     = (bf16*)alloc(1048576 * 2);
  bf16* w2b     = (bf16*)alloc(1048576 * 2);
  bf16* hb      = (bf16*)alloc((size_t)NTOK * EMB * 2);   // LN1 out; reused as y
  bf16* yb      = hb;
  float* qpb    = (float*)alloc((size_t)NROW * 32 * 4);   // reused as h2 (bf16)
  bf16* h2b     = (bf16*)qpb;
  float* kpb    = (float*)alloc((size_t)NROW * 32 * 4);   // kp; +vb reused as hid
  bf16* hidb    = (bf16*)kpb;                              // spans kpb+vb (67 MB)
  bf16* vb      = (bf16*)alloc((size_t)NROW * 64 * 2);     // contiguous after kpb
  float* kptvb  = (float*)alloc(64 * 64 * 32 * 4);
  float* kpsumb = (float*)alloc(64 * 32 * 4);              // contiguous after kptvb

  // 1) weights -> bf16
  f2b_kernel<<<48, 256, 0, stream>>>(kqv_w, kqv_wb, 12288);
  f2b_kernel<<<1024, 256, 0, stream>>>(proj_w, proj_wb, 262144);
  f2b_kernel<<<4096, 256, 0, stream>>>(mlp_w1, w1b, 1048576);
  f2b_kernel<<<4096, 256, 0, stream>>>(mlp_w2, w2b, 1048576);

  // 2) LN1: x -> h (bf16)
  ln_kernel<<<NTOK / 4, 256, 0, stream>>>(x, ln1_g, ln1_b, hb);

  // 3) fused KQV GEMM + prm_exp -> kp, qp (fp32), v (bf16)
  kqv_prm_kernel<<<NROW / 64, 256, 0, stream>>>(hb, kqv_wb, kqv_b, w, kpb, qpb, vb);

  // 4) kptv + kp_sum (atomic accumulate; zero first)
  hipMemsetAsync(kptvb, 0, (size_t)64 * 64 * 32 * 4 + 64 * 32 * 4, stream);
  kptv_kernel<<<dim3(64, 16), 256, 0, stream>>>(vb, kpb, kptvb, kpsumb);

  // 5) y (bf16, token-major [NTOK, 512]) -> reuses hb
  y_kernel<<<dim3(64, 8), 256, 0, stream>>>(qpb, kptvb, kpsumb, yb);

  // 6) proj GEMM + residual: d_out = y @ proj_w^T + proj_b + x
  gemm_bt<128, 128, 2, 2, 1><<<dim3(4, NTOK / 128), 256, 0, stream>>>(
      yb, proj_wb, proj_b, x, out, nullptr, NTOK, 512, 512);

  // 7) LN2: d_out -> h2 (bf16, reuses qp region)
  ln_kernel<<<NTOK / 4, 256, 0, stream>>>(out, ln2_g, ln2_b, h2b);

  // 8) MLP in 2 token-chunks of 16384 (hid reuses kp+v regions, 67 MB)
  for (int c = 0; c < 2; ++c) {
    const bf16* h2c = h2b + (size_t)c * 16384 * 512;
    float* outc = out + (size_t)c * 16384 * 512;
    gemm_bt<128, 128, 2, 2, 2><<<dim3(16, 128), 256, 0, stream>>>(
        h2c, w1b, mlp_b1, nullptr, nullptr, hidb, 16384, 2048, 512);
    gemm_bt<128, 128, 2, 2, 1><<<dim3(4, 128), 256, 0, stream>>>(
        hidb, w2b, mlp_b2, outc, outc, nullptr, 16384, 512, 2048);
  }
}